// Round 4
// baseline (5369.312 us; speedup 1.0000x reference)
//
#include <hip/hip_runtime.h>
#include <math.h>

#define Bsz 1024
#define Lsz 50
#define Esz 256
#define Hsz 256
#define NEGV (-1e9f)

// ============================================================
// init: copy decoder_input -> dec buffer, zero the mask
// ============================================================
__global__ void init_kernel(const float* __restrict__ dec0,
                            float* __restrict__ dec,
                            int* __restrict__ mask)
{
    int i = blockIdx.x * 256 + threadIdx.x;
    dec[i] = dec0[i];
    if (i < Bsz * Lsz) mask[i] = 0;
}

// ============================================================
// transpose the two Wq matrices once: WqT[k][n] = Wq[n][k]
// ============================================================
__global__ void transpose_wq(const float* __restrict__ WqGl, const float* __restrict__ WqPt,
                             float* __restrict__ WqGlT, float* __restrict__ WqPtT)
{
    int k = blockIdx.x;
    int n = threadIdx.x;
    if (blockIdx.y == 0) WqGlT[k * 256 + n] = WqGl[n * 256 + k];
    else                 WqPtT[k * 256 + n] = WqPt[n * 256 + k];
}

// ============================================================
// e-projection GEMM (one-time): Eo[b,l,h] = sum_k context[l,b,k]*W[h,k]+bias[h]
// grid: (4 n-tiles, 800 m-tiles) — n fastest so the 4 blocks sharing an
// A-tile are dispatch-adjacent (L2 reuse).  LDS stride 68 kills the 4-way
// write conflicts (9.8M -> ~2-way free).
// ============================================================
__global__ __launch_bounds__(256) void eproj_kernel(const float* __restrict__ A,
                                                    const float* __restrict__ W,
                                                    const float* __restrict__ bias,
                                                    float* __restrict__ Eo)
{
    __shared__ __align__(16) float As[16][68];
    __shared__ __align__(16) float Bs[16][68];
    const int tid = threadIdx.x;
    const int tx = tid & 15, ty = tid >> 4;
    const int ml = tid >> 2;
    const int kb = (tid & 3) << 2;
    const int n0 = blockIdx.x * 64, m0 = blockIdx.y * 64;
    const int K = Hsz;
    float acc[4][4] = {};
    for (int k0 = 0; k0 < K; k0 += 16) {
        float4 a4 = *(const float4*)(A + (size_t)(m0 + ml) * K + k0 + kb);
        float4 b4 = *(const float4*)(W + (size_t)(n0 + ml) * K + k0 + kb);
        As[kb+0][ml] = a4.x; As[kb+1][ml] = a4.y; As[kb+2][ml] = a4.z; As[kb+3][ml] = a4.w;
        Bs[kb+0][ml] = b4.x; Bs[kb+1][ml] = b4.y; Bs[kb+2][ml] = b4.z; Bs[kb+3][ml] = b4.w;
        __syncthreads();
#pragma unroll
        for (int kk = 0; kk < 16; kk++) {
            float4 av = *(const float4*)(&As[kk][ty << 2]);
            float4 bv = *(const float4*)(&Bs[kk][tx << 2]);
            float a_[4] = {av.x, av.y, av.z, av.w};
            float b_[4] = {bv.x, bv.y, bv.z, bv.w};
#pragma unroll
            for (int i = 0; i < 4; i++)
#pragma unroll
                for (int j = 0; j < 4; j++) acc[i][j] = fmaf(a_[i], b_[j], acc[i][j]);
        }
        __syncthreads();
    }
#pragma unroll
    for (int i = 0; i < 4; i++) {
        int m = m0 + (ty << 2) + i;
        int bb = m & (Bsz - 1);
        int ll = m >> 10;
#pragma unroll
        for (int j = 0; j < 4; j++) {
            int n = n0 + (tx << 2) + j;
            Eo[(size_t)bb * Lsz * Hsz + (size_t)ll * Hsz + n] = acc[i][j] + bias[n];
        }
    }
}

// ============================================================
// K1: fused LSTM  G = [x;h]·[Wih;Whh]^T + gate epilogue.
// LDS stride 68 (conflict fix), otherwise identical math to round 3.
// ============================================================
__global__ __launch_bounds__(256) void lstm_fused(
    const float* __restrict__ dec, const float* __restrict__ hprev,
    const float* __restrict__ cin,
    const float* __restrict__ Wih, const float* __restrict__ Whh,
    const float* __restrict__ bih, const float* __restrict__ bhh,
    float* __restrict__ hout, float* __restrict__ cout)
{
    __shared__ __align__(16) float As[16][68];
    __shared__ __align__(16) float Bs[16][68];
    const int tid = threadIdx.x;
    const int tx = tid & 15, ty = tid >> 4;
    const int ml = tid >> 2;
    const int kb = (tid & 3) << 2;
    const int m0 = blockIdx.x * 64;
    const int hh0 = blockIdx.y * 16;
    const int wrow = ((ml >> 4) << 8) + hh0 + (ml & 15);   // gate*256 + hh
    const int pcol = ((ml & 15) << 2) + (ml >> 4);         // hcol*4 + gate

    float4 a4 = *(const float4*)(dec + (size_t)(m0 + ml) * 256 + kb);
    float4 b4 = *(const float4*)(Wih + (size_t)wrow * 256 + kb);

    float acc[4][4] = {};
    for (int k0 = 0; k0 < 512; k0 += 16) {
        As[kb+0][ml] = a4.x; As[kb+1][ml] = a4.y; As[kb+2][ml] = a4.z; As[kb+3][ml] = a4.w;
        Bs[kb+0][pcol] = b4.x; Bs[kb+1][pcol] = b4.y; Bs[kb+2][pcol] = b4.z; Bs[kb+3][pcol] = b4.w;
        __syncthreads();
        int k1 = k0 + 16;
        if (k1 < 512) {
            const float* A = (k1 < 256) ? dec : hprev;
            const float* W = (k1 < 256) ? Wih : Whh;
            int kk0 = k1 & 255;
            a4 = *(const float4*)(A + (size_t)(m0 + ml) * 256 + kk0 + kb);
            b4 = *(const float4*)(W + (size_t)wrow * 256 + kk0 + kb);
        }
#pragma unroll
        for (int kk = 0; kk < 16; kk++) {
            float4 av = *(const float4*)(&As[kk][ty << 2]);
            float4 bv = *(const float4*)(&Bs[kk][tx << 2]);
            float a_[4] = {av.x, av.y, av.z, av.w};
            float b_[4] = {bv.x, bv.y, bv.z, bv.w};
#pragma unroll
            for (int i = 0; i < 4; i++)
#pragma unroll
                for (int j = 0; j < 4; j++) acc[i][j] = fmaf(a_[i], b_[j], acc[i][j]);
        }
        __syncthreads();
    }

    const int hh = hh0 + tx;
    const float bi0 = bih[hh]       + bhh[hh];
    const float bf  = bih[256 + hh] + bhh[256 + hh];
    const float bg  = bih[512 + hh] + bhh[512 + hh];
    const float bo  = bih[768 + hh] + bhh[768 + hh];
#pragma unroll
    for (int i = 0; i < 4; i++) {
        int m = m0 + (ty << 2) + i;
        float gi = acc[i][0] + bi0;
        float gf = acc[i][1] + bf;
        float gc = acc[i][2] + bg;
        float go = acc[i][3] + bo;
        float ii = 1.0f / (1.0f + expf(-gi));
        float ff = 1.0f / (1.0f + expf(-gf));
        float oo = 1.0f / (1.0f + expf(-go));
        float c2 = ff * cin[(size_t)m * 256 + hh] + ii * tanhf(gc);
        hout[(size_t)m * 256 + hh] = oo * tanhf(c2);
        cout[(size_t)m * 256 + hh] = c2;
    }
}

// ============================================================
// K2: fused glimpse + pointer attention.  512 blocks x 256 thr, 2 batch
// rows per block (halves WqT L2 traffic), ~6 KB LDS (4 blk/CU capable,
// 2 resident).  Math order bit-identical to round 3's two kernels.
// ============================================================
__global__ __launch_bounds__(256) void attn_fused(
    const float* __restrict__ h,
    const float* __restrict__ WqGlT, const float* __restrict__ glbq,
    const float* __restrict__ e_gl, const float* __restrict__ glv,
    const float* __restrict__ WqPtT, const float* __restrict__ ptbq,
    const float* __restrict__ e_pt, const float* __restrict__ ptv,
    int* __restrict__ mask, float* __restrict__ out, int t,
    float* __restrict__ dec, const float* __restrict__ emb)
{
    __shared__ float h2[2][256];
    __shared__ __align__(16) float q_s[2][256];
    __shared__ float g2[2][256];
    __shared__ float u_s[2][64];
    __shared__ float p_s[2][64];
    __shared__ int   sel_s[2];

    const int tid = threadIdx.x;
    const int lane = tid & 63, wave = tid >> 6;
    const int b0 = blockIdx.x * 2;

    h2[0][tid] = h[(size_t)b0 * 256 + tid];
    h2[1][tid] = h[(size_t)(b0 + 1) * 256 + tid];
    __syncthreads();

    // ---- glimpse query matvec (2 rows share weight stream) ----
    float q0 = glbq[tid], q1 = q0;
#pragma unroll 8
    for (int k = 0; k < 256; k++) {
        float w = WqGlT[(size_t)k * 256 + tid];
        q0 = fmaf(h2[0][k], w, q0);
        q1 = fmaf(h2[1][k], w, q1);
    }
    q_s[0][tid] = q0; q_s[1][tid] = q1;
    __syncthreads();

    const float4 vg4 = ((const float4*)glv)[lane];

    // ---- glimpse u-pass, both rows ----
#pragma unroll
    for (int r = 0; r < 2; r++) {
        const float4 q4 = ((const float4*)q_s[r])[lane];
        const float* eb = e_gl + (size_t)(b0 + r) * Lsz * 256;
#pragma unroll
        for (int lp = 0; lp < 13; lp++) {
            const int l = lp * 4 + wave;
            float x = 0.0f;
            if (l < Lsz) {
                float4 e4 = *(const float4*)(eb + (size_t)l * 256 + (lane << 2));
                x  = vg4.x * tanhf(q4.x + e4.x);
                x += vg4.y * tanhf(q4.y + e4.y);
                x += vg4.z * tanhf(q4.z + e4.z);
                x += vg4.w * tanhf(q4.w + e4.w);
            }
#pragma unroll
            for (int o = 32; o > 0; o >>= 1) x += __shfl_xor(x, o, 64);
            if (lane == 0 && l < Lsz) u_s[r][l] = x;
        }
    }
    __syncthreads();

    // ---- glimpse softmax: wave r handles row r ----
    if (wave < 2) {
        const int r = wave, l = lane;
        const int ml = (l < Lsz) ? mask[(b0 + r) * Lsz + l] : 0;
        float logit = (l < Lsz) ? (ml ? NEGV : u_s[r][l]) : -1e30f;
        float m = logit;
#pragma unroll
        for (int o = 32; o > 0; o >>= 1) m = fmaxf(m, __shfl_xor(m, o, 64));
        float ex = (l < Lsz) ? expf(logit - m) : 0.0f;
        float den = ex;
#pragma unroll
        for (int o = 32; o > 0; o >>= 1) den += __shfl_xor(den, o, 64);
        if (l < Lsz) p_s[r][l] = ex / den;
    }
    __syncthreads();

    // ---- glimpse mix (L2-hot re-read, exact l order) ----
#pragma unroll
    for (int r = 0; r < 2; r++) {
        const float* ebh = e_gl + (size_t)(b0 + r) * Lsz * 256 + tid;
        float acc = 0.0f;
#pragma unroll
        for (int l = 0; l < Lsz; l++)
            acc = fmaf(p_s[r][l], ebh[(size_t)l * 256], acc);
        g2[r][tid] = acc;
    }
    __syncthreads();

    // ---- pointer query matvec ----
    float p0 = ptbq[tid], p1 = p0;
#pragma unroll 8
    for (int k = 0; k < 256; k++) {
        float w = WqPtT[(size_t)k * 256 + tid];
        p0 = fmaf(g2[0][k], w, p0);
        p1 = fmaf(g2[1][k], w, p1);
    }
    q_s[0][tid] = p0; q_s[1][tid] = p1;
    __syncthreads();

    const float4 vp4 = ((const float4*)ptv)[lane];

    // ---- pointer u-pass, both rows ----
#pragma unroll
    for (int r = 0; r < 2; r++) {
        const float4 q4 = ((const float4*)q_s[r])[lane];
        const float* eb = e_pt + (size_t)(b0 + r) * Lsz * 256;
#pragma unroll
        for (int lp = 0; lp < 13; lp++) {
            const int l = lp * 4 + wave;
            float x = 0.0f;
            if (l < Lsz) {
                float4 e4 = *(const float4*)(eb + (size_t)l * 256 + (lane << 2));
                x  = vp4.x * tanhf(q4.x + e4.x);
                x += vp4.y * tanhf(q4.y + e4.y);
                x += vp4.z * tanhf(q4.z + e4.z);
                x += vp4.w * tanhf(q4.w + e4.w);
            }
#pragma unroll
            for (int o = 32; o > 0; o >>= 1) x += __shfl_xor(x, o, 64);
            if (lane == 0 && l < Lsz) u_s[r][l] = x;
        }
    }
    __syncthreads();

    // ---- pointer softmax + argmax + log_p + mask update ----
    if (wave < 2) {
        const int r = wave, l = lane;
        const int b = b0 + r;
        const int ml = (l < Lsz) ? mask[b * Lsz + l] : 0;
        float logit;
        if (l < Lsz) {
            float u = u_s[r][l];
            logit = 10.0f * tanhf(u);
            if (ml) logit = NEGV;
        } else logit = -1e30f;

        float m = logit;
#pragma unroll
        for (int o = 32; o > 0; o >>= 1) m = fmaxf(m, __shfl_xor(m, o, 64));
        float ex = (l < Lsz) ? expf(logit - m) : 0.0f;
        float den = ex;
#pragma unroll
        for (int o = 32; o > 0; o >>= 1) den += __shfl_xor(den, o, 64);

        // argmax with first-index tie-break
        float av = logit; int ai = (l < Lsz) ? l : 63;
#pragma unroll
        for (int o = 32; o > 0; o >>= 1) {
            float ov = __shfl_xor(av, o, 64);
            int   oi = __shfl_xor(ai, o, 64);
            if (ov > av || (ov == av && oi < ai)) { av = ov; ai = oi; }
        }
        const float lse = m + logf(den);
        if (l < Lsz)
            out[(size_t)b * Lsz * Lsz + (size_t)t * Lsz + l] = logit - lse;
        if (l == 0) {
            out[(size_t)Bsz * Lsz * Lsz + (size_t)b * Lsz + t] = (float)ai;
            sel_s[r] = ai;
        }
        int newm = ml | (l == ai);
        unsigned long long bal = __ballot(l >= Lsz ? 1 : newm);
        int all = (bal == 0xFFFFFFFFFFFFFFFFull);
        if (l < Lsz) mask[b * Lsz + l] = (all && l == Lsz - 1) ? 0 : newm;
    }
    __syncthreads();

    // ---- gather next decoder input for both rows ----
#pragma unroll
    for (int r = 0; r < 2; r++) {
        const int s = sel_s[r];
        dec[(size_t)(b0 + r) * 256 + tid] =
            emb[(size_t)s * Bsz * 256 + (size_t)(b0 + r) * 256 + tid];
    }
}

// ============================================================
extern "C" void kernel_launch(void* const* d_in, const int* in_sizes, int n_in,
                              void* d_out, int out_size, void* d_ws, size_t ws_size,
                              hipStream_t stream) {
    const float* decoder_input = (const float*)d_in[0];
    const float* emb           = (const float*)d_in[1];   // [L,B,E]
    const float* h0            = (const float*)d_in[2];
    const float* c0            = (const float*)d_in[3];
    const float* context       = (const float*)d_in[4];   // [L,B,H]
    const float* Wih    = (const float*)d_in[6];
    const float* Whh    = (const float*)d_in[7];
    const float* bih    = (const float*)d_in[8];
    const float* bhh    = (const float*)d_in[9];
    const float* glWq   = (const float*)d_in[10];
    const float* glbq   = (const float*)d_in[11];
    const float* glWref = (const float*)d_in[12];
    const float* glbref = (const float*)d_in[13];
    const float* glv    = (const float*)d_in[14];
    const float* ptWq   = (const float*)d_in[15];
    const float* ptbq   = (const float*)d_in[16];
    const float* ptWref = (const float*)d_in[17];
    const float* ptbref = (const float*)d_in[18];
    const float* ptv    = (const float*)d_in[19];

    float* out = (float*)d_out;

    // workspace layout (floats)
    float* ws    = (float*)d_ws;
    float* e_gl  = ws;                                    // [B,L,H]
    float* e_pt  = e_gl + (size_t)Bsz * Lsz * Hsz;        // [B,L,H]
    float* WqGlT = e_pt + (size_t)Bsz * Lsz * Hsz;        // [H,H]
    float* WqPtT = WqGlT + (size_t)Hsz * Hsz;
    float* hb0   = WqPtT + (size_t)Hsz * Hsz;
    float* hb1   = hb0 + (size_t)Bsz * Hsz;
    float* cb0   = hb1 + (size_t)Bsz * Hsz;
    float* cb1   = cb0 + (size_t)Bsz * Hsz;
    float* dec   = cb1 + (size_t)Bsz * Hsz;
    int*   mask  = (int*)(dec + (size_t)Bsz * Esz);       // [B,L]

    float* hbuf[2] = {hb0, hb1};
    float* cbuf[2] = {cb0, cb1};

    init_kernel<<<dim3(Bsz), dim3(256), 0, stream>>>(decoder_input, dec, mask);
    transpose_wq<<<dim3(256, 2), dim3(256), 0, stream>>>(glWq, ptWq, WqGlT, WqPtT);

    dim3 ge(Hsz / 64, Lsz * Bsz / 64);   // n-tiles fastest -> A-tile L2 reuse
    eproj_kernel<<<ge, dim3(256), 0, stream>>>(context, glWref, glbref, e_gl);
    eproj_kernel<<<ge, dim3(256), 0, stream>>>(context, ptWref, ptbref, e_pt);

    for (int t = 0; t < Lsz; t++) {
        const float* hin = (t == 0) ? h0 : hbuf[(t + 1) & 1];
        const float* cin = (t == 0) ? c0 : cbuf[(t + 1) & 1];
        float* hout = hbuf[t & 1];
        float* cout = cbuf[t & 1];

        lstm_fused<<<dim3(16, 16), dim3(256), 0, stream>>>(
            dec, hin, cin, Wih, Whh, bih, bhh, hout, cout);

        attn_fused<<<dim3(512), dim3(256), 0, stream>>>(
            hout, WqGlT, glbq, e_gl, glv, WqPtT, ptbq, e_pt, ptv,
            mask, out, t, dec, emb);
    }
}

// Round 5
// 4382.762 us; speedup vs baseline: 1.2251x; 1.2251x over previous
//
#include <hip/hip_runtime.h>
#include <math.h>

#define Bsz 1024
#define Lsz 50
#define Esz 256
#define Hsz 256
#define NEGV (-1e9f)

// ============================================================
// init: copy decoder_input -> dec buffer, zero the mask
// ============================================================
__global__ void init_kernel(const float* __restrict__ dec0,
                            float* __restrict__ dec,
                            int* __restrict__ mask)
{
    int i = blockIdx.x * 256 + threadIdx.x;
    dec[i] = dec0[i];
    if (i < Bsz * Lsz) mask[i] = 0;
}

// ============================================================
// transpose the two Wq matrices once: WqT[k][n] = Wq[n][k]
// ============================================================
__global__ void transpose_wq(const float* __restrict__ WqGl, const float* __restrict__ WqPt,
                             float* __restrict__ WqGlT, float* __restrict__ WqPtT)
{
    int k = blockIdx.x;
    int n = threadIdx.x;
    if (blockIdx.y == 0) WqGlT[k * 256 + n] = WqGl[n * 256 + k];
    else                 WqPtT[k * 256 + n] = WqPt[n * 256 + k];
}

// ============================================================
// e-projection GEMM (one-time): Eo[b,l,h] = sum_k context[l,b,k]*W[h,k]+bias[h]
// Linear grid 3200, XCD-aware swizzle: xcd = blk&7 owns m-tiles
// [xcd*100, xcd*100+100); the 4 n-tiles of one A-tile are consecutive
// within the XCD so the A-tile is fetched into that XCD's L2 once.
// LDS stride 68 (4-way conflict fix, verified 9.8M->3.3M).
// ============================================================
__global__ __launch_bounds__(256) void eproj_kernel(const float* __restrict__ A,
                                                    const float* __restrict__ W,
                                                    const float* __restrict__ bias,
                                                    float* __restrict__ Eo)
{
    __shared__ __align__(16) float As[16][68];
    __shared__ __align__(16) float Bs[16][68];
    const int tid = threadIdx.x;
    const int tx = tid & 15, ty = tid >> 4;
    const int ml = tid >> 2;
    const int kb = (tid & 3) << 2;

    const int x = blockIdx.x;
    const int xcd = x & 7;
    const int j = x >> 3;              // [0,400)
    const int mt = xcd * 100 + (j >> 2);
    const int nt = j & 3;
    const int m0 = mt * 64, n0 = nt * 64;

    const int K = Hsz;
    float acc[4][4] = {};
    for (int k0 = 0; k0 < K; k0 += 16) {
        float4 a4 = *(const float4*)(A + (size_t)(m0 + ml) * K + k0 + kb);
        float4 b4 = *(const float4*)(W + (size_t)(n0 + ml) * K + k0 + kb);
        As[kb+0][ml] = a4.x; As[kb+1][ml] = a4.y; As[kb+2][ml] = a4.z; As[kb+3][ml] = a4.w;
        Bs[kb+0][ml] = b4.x; Bs[kb+1][ml] = b4.y; Bs[kb+2][ml] = b4.z; Bs[kb+3][ml] = b4.w;
        __syncthreads();
#pragma unroll
        for (int kk = 0; kk < 16; kk++) {
            float4 av = *(const float4*)(&As[kk][ty << 2]);
            float4 bv = *(const float4*)(&Bs[kk][tx << 2]);
            float a_[4] = {av.x, av.y, av.z, av.w};
            float b_[4] = {bv.x, bv.y, bv.z, bv.w};
#pragma unroll
            for (int i = 0; i < 4; i++)
#pragma unroll
                for (int j2 = 0; j2 < 4; j2++) acc[i][j2] = fmaf(a_[i], b_[j2], acc[i][j2]);
        }
        __syncthreads();
    }
#pragma unroll
    for (int i = 0; i < 4; i++) {
        int m = m0 + (ty << 2) + i;
        int bb = m & (Bsz - 1);
        int ll = m >> 10;
#pragma unroll
        for (int j2 = 0; j2 < 4; j2++) {
            int n = n0 + (tx << 2) + j2;
            Eo[(size_t)bb * Lsz * Hsz + (size_t)ll * Hsz + n] = acc[i][j2] + bias[n];
        }
    }
}

// ============================================================
// K1: fused LSTM  G = [x;h]·[Wih;Whh]^T + gate epilogue (unchanged).
// ============================================================
__global__ __launch_bounds__(256) void lstm_fused(
    const float* __restrict__ dec, const float* __restrict__ hprev,
    const float* __restrict__ cin,
    const float* __restrict__ Wih, const float* __restrict__ Whh,
    const float* __restrict__ bih, const float* __restrict__ bhh,
    float* __restrict__ hout, float* __restrict__ cout)
{
    __shared__ __align__(16) float As[16][68];
    __shared__ __align__(16) float Bs[16][68];
    const int tid = threadIdx.x;
    const int tx = tid & 15, ty = tid >> 4;
    const int ml = tid >> 2;
    const int kb = (tid & 3) << 2;
    const int m0 = blockIdx.x * 64;
    const int hh0 = blockIdx.y * 16;
    const int wrow = ((ml >> 4) << 8) + hh0 + (ml & 15);   // gate*256 + hh
    const int pcol = ((ml & 15) << 2) + (ml >> 4);         // hcol*4 + gate

    float4 a4 = *(const float4*)(dec + (size_t)(m0 + ml) * 256 + kb);
    float4 b4 = *(const float4*)(Wih + (size_t)wrow * 256 + kb);

    float acc[4][4] = {};
    for (int k0 = 0; k0 < 512; k0 += 16) {
        As[kb+0][ml] = a4.x; As[kb+1][ml] = a4.y; As[kb+2][ml] = a4.z; As[kb+3][ml] = a4.w;
        Bs[kb+0][pcol] = b4.x; Bs[kb+1][pcol] = b4.y; Bs[kb+2][pcol] = b4.z; Bs[kb+3][pcol] = b4.w;
        __syncthreads();
        int k1 = k0 + 16;
        if (k1 < 512) {
            const float* A = (k1 < 256) ? dec : hprev;
            const float* W = (k1 < 256) ? Wih : Whh;
            int kk0 = k1 & 255;
            a4 = *(const float4*)(A + (size_t)(m0 + ml) * 256 + kk0 + kb);
            b4 = *(const float4*)(W + (size_t)wrow * 256 + kk0 + kb);
        }
#pragma unroll
        for (int kk = 0; kk < 16; kk++) {
            float4 av = *(const float4*)(&As[kk][ty << 2]);
            float4 bv = *(const float4*)(&Bs[kk][tx << 2]);
            float a_[4] = {av.x, av.y, av.z, av.w};
            float b_[4] = {bv.x, bv.y, bv.z, bv.w};
#pragma unroll
            for (int i = 0; i < 4; i++)
#pragma unroll
                for (int j = 0; j < 4; j++) acc[i][j] = fmaf(a_[i], b_[j], acc[i][j]);
        }
        __syncthreads();
    }

    const int hh = hh0 + tx;
    const float bi0 = bih[hh]       + bhh[hh];
    const float bf  = bih[256 + hh] + bhh[256 + hh];
    const float bg  = bih[512 + hh] + bhh[512 + hh];
    const float bo  = bih[768 + hh] + bhh[768 + hh];
#pragma unroll
    for (int i = 0; i < 4; i++) {
        int m = m0 + (ty << 2) + i;
        float gi = acc[i][0] + bi0;
        float gf = acc[i][1] + bf;
        float gc = acc[i][2] + bg;
        float go = acc[i][3] + bo;
        float ii = 1.0f / (1.0f + expf(-gi));
        float ff = 1.0f / (1.0f + expf(-gf));
        float oo = 1.0f / (1.0f + expf(-go));
        float c2 = ff * cin[(size_t)m * 256 + hh] + ii * tanhf(gc);
        hout[(size_t)m * 256 + hh] = oo * tanhf(c2);
        cout[(size_t)m * 256 + hh] = c2;
    }
}

// ============================================================
// K2: fused glimpse + pointer attention, ONE ROW PER BLOCK (1024 blocks,
// round-3 parallelism + round-4 launch saving).  ~3.5 KB LDS.
// Per-row math is bit-identical to round 3's two attn kernels; g passes
// through LDS instead of global.
// ============================================================
__global__ __launch_bounds__(256) void attn_row(
    const float* __restrict__ h,
    const float* __restrict__ WqGlT, const float* __restrict__ glbq,
    const float* __restrict__ e_gl, const float* __restrict__ glv,
    const float* __restrict__ WqPtT, const float* __restrict__ ptbq,
    const float* __restrict__ e_pt, const float* __restrict__ ptv,
    int* __restrict__ mask, float* __restrict__ out, int t,
    float* __restrict__ dec, const float* __restrict__ emb)
{
    __shared__ float h_s[256];
    __shared__ __align__(16) float q_s[256];
    __shared__ float g_s[256];
    __shared__ float u_s[64];
    __shared__ float p_s[64];
    __shared__ int sel_s;

    const int tid = threadIdx.x;
    const int lane = tid & 63, wave = tid >> 6;
    const int b = blockIdx.x;

    h_s[tid] = h[(size_t)b * 256 + tid];
    __syncthreads();

    // ---- glimpse query matvec ----
    float q = glbq[tid];
#pragma unroll 8
    for (int k = 0; k < 256; k++)
        q = fmaf(h_s[k], WqGlT[(size_t)k * 256 + tid], q);
    q_s[tid] = q;
    __syncthreads();

    const float* ebg = e_gl + (size_t)b * Lsz * 256;
    {
        const float4 q4 = ((const float4*)q_s)[lane];
        const float4 v4 = ((const float4*)glv)[lane];
        // ---- glimpse u-pass ----
#pragma unroll
        for (int lp = 0; lp < 13; lp++) {
            const int l = lp * 4 + wave;
            float x = 0.0f;
            if (l < Lsz) {
                float4 e4 = *(const float4*)(ebg + (size_t)l * 256 + (lane << 2));
                x  = v4.x * tanhf(q4.x + e4.x);
                x += v4.y * tanhf(q4.y + e4.y);
                x += v4.z * tanhf(q4.z + e4.z);
                x += v4.w * tanhf(q4.w + e4.w);
            }
#pragma unroll
            for (int o = 32; o > 0; o >>= 1) x += __shfl_xor(x, o, 64);
            if (lane == 0 && l < Lsz) u_s[l] = x;
        }
    }
    __syncthreads();

    // ---- glimpse softmax (wave 0, lane-parallel) ----
    if (wave == 0) {
        const int l = lane;
        const int ml = (l < Lsz) ? mask[b * Lsz + l] : 0;
        float logit = (l < Lsz) ? (ml ? NEGV : u_s[l]) : -1e30f;
        float m = logit;
#pragma unroll
        for (int o = 32; o > 0; o >>= 1) m = fmaxf(m, __shfl_xor(m, o, 64));
        float ex = (l < Lsz) ? expf(logit - m) : 0.0f;
        float den = ex;
#pragma unroll
        for (int o = 32; o > 0; o >>= 1) den += __shfl_xor(den, o, 64);
        if (l < Lsz) p_s[l] = ex / den;
    }
    __syncthreads();

    // ---- glimpse mix (L2-hot re-read, exact l order) ----
    {
        float acc = 0.0f;
        const float* ebh = ebg + tid;
#pragma unroll
        for (int l = 0; l < Lsz; l++)
            acc = fmaf(p_s[l], ebh[(size_t)l * 256], acc);
        g_s[tid] = acc;
    }
    __syncthreads();

    // ---- pointer query matvec ----
    float p = ptbq[tid];
#pragma unroll 8
    for (int k = 0; k < 256; k++)
        p = fmaf(g_s[k], WqPtT[(size_t)k * 256 + tid], p);
    q_s[tid] = p;
    __syncthreads();

    const float* ebp = e_pt + (size_t)b * Lsz * 256;
    {
        const float4 q4 = ((const float4*)q_s)[lane];
        const float4 v4 = ((const float4*)ptv)[lane];
        // ---- pointer u-pass ----
#pragma unroll
        for (int lp = 0; lp < 13; lp++) {
            const int l = lp * 4 + wave;
            float x = 0.0f;
            if (l < Lsz) {
                float4 e4 = *(const float4*)(ebp + (size_t)l * 256 + (lane << 2));
                x  = v4.x * tanhf(q4.x + e4.x);
                x += v4.y * tanhf(q4.y + e4.y);
                x += v4.z * tanhf(q4.z + e4.z);
                x += v4.w * tanhf(q4.w + e4.w);
            }
#pragma unroll
            for (int o = 32; o > 0; o >>= 1) x += __shfl_xor(x, o, 64);
            if (lane == 0 && l < Lsz) u_s[l] = x;
        }
    }
    __syncthreads();

    // ---- pointer softmax + argmax + log_p + mask update (wave 0) ----
    if (wave == 0) {
        const int l = lane;
        const int ml = (l < Lsz) ? mask[b * Lsz + l] : 0;
        float logit;
        if (l < Lsz) {
            float u = u_s[l];
            logit = 10.0f * tanhf(u);
            if (ml) logit = NEGV;
        } else logit = -1e30f;

        float m = logit;
#pragma unroll
        for (int o = 32; o > 0; o >>= 1) m = fmaxf(m, __shfl_xor(m, o, 64));
        float ex = (l < Lsz) ? expf(logit - m) : 0.0f;
        float den = ex;
#pragma unroll
        for (int o = 32; o > 0; o >>= 1) den += __shfl_xor(den, o, 64);

        // argmax with first-index tie-break
        float av = logit; int ai = (l < Lsz) ? l : 63;
#pragma unroll
        for (int o = 32; o > 0; o >>= 1) {
            float ov = __shfl_xor(av, o, 64);
            int   oi = __shfl_xor(ai, o, 64);
            if (ov > av || (ov == av && oi < ai)) { av = ov; ai = oi; }
        }
        const float lse = m + logf(den);
        if (l < Lsz)
            out[(size_t)b * Lsz * Lsz + (size_t)t * Lsz + l] = logit - lse;
        if (l == 0) {
            out[(size_t)Bsz * Lsz * Lsz + (size_t)b * Lsz + t] = (float)ai;
            sel_s = ai;
        }
        int newm = ml | (l == ai);
        unsigned long long bal = __ballot(l >= Lsz ? 1 : newm);
        int all = (bal == 0xFFFFFFFFFFFFFFFFull);
        if (l < Lsz) mask[b * Lsz + l] = (all && l == Lsz - 1) ? 0 : newm;
    }
    __syncthreads();

    // ---- gather next decoder input ----
    {
        const int s = sel_s;
        dec[(size_t)b * 256 + tid] = emb[(size_t)s * Bsz * 256 + (size_t)b * 256 + tid];
    }
}

// ============================================================
extern "C" void kernel_launch(void* const* d_in, const int* in_sizes, int n_in,
                              void* d_out, int out_size, void* d_ws, size_t ws_size,
                              hipStream_t stream) {
    const float* decoder_input = (const float*)d_in[0];
    const float* emb           = (const float*)d_in[1];   // [L,B,E]
    const float* h0            = (const float*)d_in[2];
    const float* c0            = (const float*)d_in[3];
    const float* context       = (const float*)d_in[4];   // [L,B,H]
    const float* Wih    = (const float*)d_in[6];
    const float* Whh    = (const float*)d_in[7];
    const float* bih    = (const float*)d_in[8];
    const float* bhh    = (const float*)d_in[9];
    const float* glWq   = (const float*)d_in[10];
    const float* glbq   = (const float*)d_in[11];
    const float* glWref = (const float*)d_in[12];
    const float* glbref = (const float*)d_in[13];
    const float* glv    = (const float*)d_in[14];
    const float* ptWq   = (const float*)d_in[15];
    const float* ptbq   = (const float*)d_in[16];
    const float* ptWref = (const float*)d_in[17];
    const float* ptbref = (const float*)d_in[18];
    const float* ptv    = (const float*)d_in[19];

    float* out = (float*)d_out;

    // workspace layout (floats)
    float* ws    = (float*)d_ws;
    float* e_gl  = ws;                                    // [B,L,H]
    float* e_pt  = e_gl + (size_t)Bsz * Lsz * Hsz;        // [B,L,H]
    float* WqGlT = e_pt + (size_t)Bsz * Lsz * Hsz;        // [H,H]
    float* WqPtT = WqGlT + (size_t)Hsz * Hsz;
    float* hb0   = WqPtT + (size_t)Hsz * Hsz;
    float* hb1   = hb0 + (size_t)Bsz * Hsz;
    float* cb0   = hb1 + (size_t)Bsz * Hsz;
    float* cb1   = cb0 + (size_t)Bsz * Hsz;
    float* dec   = cb1 + (size_t)Bsz * Hsz;
    int*   mask  = (int*)(dec + (size_t)Bsz * Esz);       // [B,L]

    float* hbuf[2] = {hb0, hb1};
    float* cbuf[2] = {cb0, cb1};

    init_kernel<<<dim3(Bsz), dim3(256), 0, stream>>>(decoder_input, dec, mask);
    transpose_wq<<<dim3(256, 2), dim3(256), 0, stream>>>(glWq, ptWq, WqGlT, WqPtT);

    eproj_kernel<<<dim3(3200), dim3(256), 0, stream>>>(context, glWref, glbref, e_gl);
    eproj_kernel<<<dim3(3200), dim3(256), 0, stream>>>(context, ptWref, ptbref, e_pt);

    for (int t = 0; t < Lsz; t++) {
        const float* hin = (t == 0) ? h0 : hbuf[(t + 1) & 1];
        const float* cin = (t == 0) ? c0 : cbuf[(t + 1) & 1];
        float* hout = hbuf[t & 1];
        float* cout = cbuf[t & 1];

        lstm_fused<<<dim3(16, 16), dim3(256), 0, stream>>>(
            dec, hin, cin, Wih, Whh, bih, bhh, hout, cout);

        attn_row<<<dim3(Bsz), dim3(256), 0, stream>>>(
            hout, WqGlT, glbq, e_gl, glv, WqPtT, ptbq, e_pt, ptv,
            mask, out, t, dec, emb);
    }
}

// Round 6
// 4145.067 us; speedup vs baseline: 1.2953x; 1.0573x over previous
//
#include <hip/hip_runtime.h>
#include <math.h>

#define Bsz 1024
#define Lsz 50
#define Esz 256
#define Hsz 256
#define NEGV (-1e9f)

// ============================================================
// init: copy decoder_input -> dec buffer, zero the mask
// ============================================================
__global__ void init_kernel(const float* __restrict__ dec0,
                            float* __restrict__ dec,
                            int* __restrict__ mask)
{
    int i = blockIdx.x * 256 + threadIdx.x;
    dec[i] = dec0[i];
    if (i < Bsz * Lsz) mask[i] = 0;
}

// ============================================================
// pack the two Wq matrices k-major once:
// Wpk[((k>>2)*256 + n)*4 + (k&3)] = Wq[n][k]
// so a float4 at [k4*256+n] holds Wq[n][4k4..4k4+3]
// ============================================================
__global__ void pack_wq(const float* __restrict__ WqGl, const float* __restrict__ WqPt,
                        float* __restrict__ WqGlP, float* __restrict__ WqPtP)
{
    int k = blockIdx.x;
    int n = threadIdx.x;
    const float* src = blockIdx.y ? WqPt : WqGl;
    float*       dst = blockIdx.y ? WqPtP : WqGlP;
    dst[((size_t)(k >> 2) * 256 + n) * 4 + (k & 3)] = src[(size_t)n * 256 + k];
}

// ============================================================
// e-projection GEMM (one-time), BOTH matrices in one launch.
// grid 6400: xcd = x&7 owns m-tiles [xcd*100, +100); per XCD the 8 blocks
// (2 sel x 4 nt) of one A-tile are consecutive -> A fetched once into that
// XCD's L2.  Register prefetch hides global latency (lstm_fused pattern).
// LDS stride 68 (conflict fix).
// ============================================================
__global__ __launch_bounds__(256) void eproj_kernel(
    const float* __restrict__ A,
    const float* __restrict__ Wgl, const float* __restrict__ bgl, float* __restrict__ Egl,
    const float* __restrict__ Wpt, const float* __restrict__ bpt, float* __restrict__ Ept)
{
    __shared__ __align__(16) float As[16][68];
    __shared__ __align__(16) float Bs[16][68];
    const int tid = threadIdx.x;
    const int tx = tid & 15, ty = tid >> 4;
    const int ml = tid >> 2;
    const int kb = (tid & 3) << 2;

    const int x = blockIdx.x;
    const int xcd = x & 7;
    const int j = x >> 3;                 // [0,800)
    const int mt = xcd * 100 + (j >> 3);  // m-tile
    const int sel = (j >> 2) & 1;         // 0 = glimpse, 1 = pointer
    const int nt = j & 3;
    const float* W    = sel ? Wpt : Wgl;
    const float* bias = sel ? bpt : bgl;
    float*       Eo   = sel ? Ept : Egl;
    const int m0 = mt * 64, n0 = nt * 64;

    float4 a4 = *(const float4*)(A + (size_t)(m0 + ml) * 256 + kb);
    float4 b4 = *(const float4*)(W + (size_t)(n0 + ml) * 256 + kb);

    float acc[4][4] = {};
    for (int k0 = 0; k0 < 256; k0 += 16) {
        As[kb+0][ml] = a4.x; As[kb+1][ml] = a4.y; As[kb+2][ml] = a4.z; As[kb+3][ml] = a4.w;
        Bs[kb+0][ml] = b4.x; Bs[kb+1][ml] = b4.y; Bs[kb+2][ml] = b4.z; Bs[kb+3][ml] = b4.w;
        __syncthreads();
        int k1 = k0 + 16;
        if (k1 < 256) {
            a4 = *(const float4*)(A + (size_t)(m0 + ml) * 256 + k1 + kb);
            b4 = *(const float4*)(W + (size_t)(n0 + ml) * 256 + k1 + kb);
        }
#pragma unroll
        for (int kk = 0; kk < 16; kk++) {
            float4 av = *(const float4*)(&As[kk][ty << 2]);
            float4 bv = *(const float4*)(&Bs[kk][tx << 2]);
            float a_[4] = {av.x, av.y, av.z, av.w};
            float b_[4] = {bv.x, bv.y, bv.z, bv.w};
#pragma unroll
            for (int i = 0; i < 4; i++)
#pragma unroll
                for (int j2 = 0; j2 < 4; j2++) acc[i][j2] = fmaf(a_[i], b_[j2], acc[i][j2]);
        }
        __syncthreads();
    }
#pragma unroll
    for (int i = 0; i < 4; i++) {
        int m = m0 + (ty << 2) + i;
        int bb = m & (Bsz - 1);
        int ll = m >> 10;
#pragma unroll
        for (int j2 = 0; j2 < 4; j2++) {
            int n = n0 + (tx << 2) + j2;
            Eo[(size_t)bb * Lsz * Hsz + (size_t)ll * Hsz + n] = acc[i][j2] + bias[n];
        }
    }
}

// ============================================================
// K1: fused LSTM, 32 rows x 64 gate-cols per block -> 512 blocks (2/CU,
// was 1/CU: barriers idled the CU).  K-order identical -> bit-identical h.
// Column permutation pcol = hcol*4+gate as before; acc[2][4] micro-tile.
// ============================================================
__global__ __launch_bounds__(256) void lstm_fused(
    const float* __restrict__ dec, const float* __restrict__ hprev,
    const float* __restrict__ cin,
    const float* __restrict__ Wih, const float* __restrict__ Whh,
    const float* __restrict__ bih, const float* __restrict__ bhh,
    float* __restrict__ hout, float* __restrict__ cout)
{
    __shared__ __align__(16) float As[16][36];
    __shared__ __align__(16) float Bs[16][68];
    const int tid = threadIdx.x;
    const int tx = tid & 15, ty = tid >> 4;      // ty: 2 rows each
    const int mlA = tid >> 3;                    // [0,32)
    const int kbA = (tid & 7) << 1;              // {0,2,..,14}
    const int mlB = tid >> 2;                    // [0,64)
    const int kbB = (tid & 3) << 2;
    const int m0 = blockIdx.x * 32;
    const int hh0 = blockIdx.y * 16;
    const int wrow = ((mlB >> 4) << 8) + hh0 + (mlB & 15);   // gate*256 + hh
    const int pcol = ((mlB & 15) << 2) + (mlB >> 4);         // hcol*4 + gate

    float2 a2 = *(const float2*)(dec + (size_t)(m0 + mlA) * 256 + kbA);
    float4 b4 = *(const float4*)(Wih + (size_t)wrow * 256 + kbB);

    float acc[2][4] = {};
    for (int k0 = 0; k0 < 512; k0 += 16) {
        As[kbA+0][mlA] = a2.x; As[kbA+1][mlA] = a2.y;
        Bs[kbB+0][pcol] = b4.x; Bs[kbB+1][pcol] = b4.y;
        Bs[kbB+2][pcol] = b4.z; Bs[kbB+3][pcol] = b4.w;
        __syncthreads();
        int k1 = k0 + 16;
        if (k1 < 512) {
            const float* Ap = (k1 < 256) ? dec : hprev;
            const float* Wp = (k1 < 256) ? Wih : Whh;
            int kk0 = k1 & 255;
            a2 = *(const float2*)(Ap + (size_t)(m0 + mlA) * 256 + kk0 + kbA);
            b4 = *(const float4*)(Wp + (size_t)wrow * 256 + kk0 + kbB);
        }
#pragma unroll
        for (int kk = 0; kk < 16; kk++) {
            float2 av = *(const float2*)(&As[kk][ty << 1]);
            float4 bv = *(const float4*)(&Bs[kk][tx << 2]);
            acc[0][0] = fmaf(av.x, bv.x, acc[0][0]);
            acc[0][1] = fmaf(av.x, bv.y, acc[0][1]);
            acc[0][2] = fmaf(av.x, bv.z, acc[0][2]);
            acc[0][3] = fmaf(av.x, bv.w, acc[0][3]);
            acc[1][0] = fmaf(av.y, bv.x, acc[1][0]);
            acc[1][1] = fmaf(av.y, bv.y, acc[1][1]);
            acc[1][2] = fmaf(av.y, bv.z, acc[1][2]);
            acc[1][3] = fmaf(av.y, bv.w, acc[1][3]);
        }
        __syncthreads();
    }

    const int hh = hh0 + tx;
    const float bi0 = bih[hh]       + bhh[hh];
    const float bf  = bih[256 + hh] + bhh[256 + hh];
    const float bg  = bih[512 + hh] + bhh[512 + hh];
    const float bo  = bih[768 + hh] + bhh[768 + hh];
#pragma unroll
    for (int i = 0; i < 2; i++) {
        int m = m0 + (ty << 1) + i;
        float gi = acc[i][0] + bi0;
        float gf = acc[i][1] + bf;
        float gc = acc[i][2] + bg;
        float go = acc[i][3] + bo;
        float ii = 1.0f / (1.0f + expf(-gi));
        float ff = 1.0f / (1.0f + expf(-gf));
        float oo = 1.0f / (1.0f + expf(-go));
        float c2 = ff * cin[(size_t)m * 256 + hh] + ii * tanhf(gc);
        hout[(size_t)m * 256 + hh] = oo * tanhf(c2);
        cout[(size_t)m * 256 + hh] = c2;
    }
}

// ============================================================
// K2: fused glimpse + pointer attention, one row per block (1024 blocks).
// Matvec uses k-major packed Wq: 64 x (dwordx4 + b128 h-broadcast + 4 FMA),
// ascending-k order (bit-identical to round 5).
// ============================================================
__global__ __launch_bounds__(256) void attn_row(
    const float* __restrict__ h,
    const float* __restrict__ WqGlP, const float* __restrict__ glbq,
    const float* __restrict__ e_gl, const float* __restrict__ glv,
    const float* __restrict__ WqPtP, const float* __restrict__ ptbq,
    const float* __restrict__ e_pt, const float* __restrict__ ptv,
    int* __restrict__ mask, float* __restrict__ out, int t,
    float* __restrict__ dec, const float* __restrict__ emb)
{
    __shared__ __align__(16) float h_s[256];
    __shared__ __align__(16) float q_s[256];
    __shared__ __align__(16) float g_s[256];
    __shared__ float u_s[64];
    __shared__ float p_s[64];
    __shared__ int sel_s;

    const int tid = threadIdx.x;
    const int lane = tid & 63, wave = tid >> 6;
    const int b = blockIdx.x;

    h_s[tid] = h[(size_t)b * 256 + tid];
    __syncthreads();

    // ---- glimpse query matvec (packed weights) ----
    {
        float q = glbq[tid];
        const float4* Wp = (const float4*)WqGlP;
#pragma unroll 8
        for (int k4 = 0; k4 < 64; k4++) {
            float4 w  = Wp[(size_t)k4 * 256 + tid];
            float4 hv = ((const float4*)h_s)[k4];
            q = fmaf(hv.x, w.x, q);
            q = fmaf(hv.y, w.y, q);
            q = fmaf(hv.z, w.z, q);
            q = fmaf(hv.w, w.w, q);
        }
        q_s[tid] = q;
    }
    __syncthreads();

    const float* ebg = e_gl + (size_t)b * Lsz * 256;
    {
        const float4 q4 = ((const float4*)q_s)[lane];
        const float4 v4 = ((const float4*)glv)[lane];
#pragma unroll
        for (int lp = 0; lp < 13; lp++) {
            const int l = lp * 4 + wave;
            float x = 0.0f;
            if (l < Lsz) {
                float4 e4 = *(const float4*)(ebg + (size_t)l * 256 + (lane << 2));
                x  = v4.x * tanhf(q4.x + e4.x);
                x += v4.y * tanhf(q4.y + e4.y);
                x += v4.z * tanhf(q4.z + e4.z);
                x += v4.w * tanhf(q4.w + e4.w);
            }
#pragma unroll
            for (int o = 32; o > 0; o >>= 1) x += __shfl_xor(x, o, 64);
            if (lane == 0 && l < Lsz) u_s[l] = x;
        }
    }
    __syncthreads();

    // ---- glimpse softmax (wave 0, lane-parallel) ----
    if (wave == 0) {
        const int l = lane;
        const int ml = (l < Lsz) ? mask[b * Lsz + l] : 0;
        float logit = (l < Lsz) ? (ml ? NEGV : u_s[l]) : -1e30f;
        float m = logit;
#pragma unroll
        for (int o = 32; o > 0; o >>= 1) m = fmaxf(m, __shfl_xor(m, o, 64));
        float ex = (l < Lsz) ? expf(logit - m) : 0.0f;
        float den = ex;
#pragma unroll
        for (int o = 32; o > 0; o >>= 1) den += __shfl_xor(den, o, 64);
        if (l < Lsz) p_s[l] = ex / den;
    }
    __syncthreads();

    // ---- glimpse mix (L2-hot re-read, exact l order) ----
    {
        float acc = 0.0f;
        const float* ebh = ebg + tid;
#pragma unroll
        for (int l = 0; l < Lsz; l++)
            acc = fmaf(p_s[l], ebh[(size_t)l * 256], acc);
        g_s[tid] = acc;
    }
    __syncthreads();

    // ---- pointer query matvec (packed weights) ----
    {
        float p = ptbq[tid];
        const float4* Wp = (const float4*)WqPtP;
#pragma unroll 8
        for (int k4 = 0; k4 < 64; k4++) {
            float4 w  = Wp[(size_t)k4 * 256 + tid];
            float4 gv = ((const float4*)g_s)[k4];
            p = fmaf(gv.x, w.x, p);
            p = fmaf(gv.y, w.y, p);
            p = fmaf(gv.z, w.z, p);
            p = fmaf(gv.w, w.w, p);
        }
        q_s[tid] = p;
    }
    __syncthreads();

    const float* ebp = e_pt + (size_t)b * Lsz * 256;
    {
        const float4 q4 = ((const float4*)q_s)[lane];
        const float4 v4 = ((const float4*)ptv)[lane];
#pragma unroll
        for (int lp = 0; lp < 13; lp++) {
            const int l = lp * 4 + wave;
            float x = 0.0f;
            if (l < Lsz) {
                float4 e4 = *(const float4*)(ebp + (size_t)l * 256 + (lane << 2));
                x  = v4.x * tanhf(q4.x + e4.x);
                x += v4.y * tanhf(q4.y + e4.y);
                x += v4.z * tanhf(q4.z + e4.z);
                x += v4.w * tanhf(q4.w + e4.w);
            }
#pragma unroll
            for (int o = 32; o > 0; o >>= 1) x += __shfl_xor(x, o, 64);
            if (lane == 0 && l < Lsz) u_s[l] = x;
        }
    }
    __syncthreads();

    // ---- pointer softmax + argmax + log_p + mask update (wave 0) ----
    if (wave == 0) {
        const int l = lane;
        const int ml = (l < Lsz) ? mask[b * Lsz + l] : 0;
        float logit;
        if (l < Lsz) {
            float u = u_s[l];
            logit = 10.0f * tanhf(u);
            if (ml) logit = NEGV;
        } else logit = -1e30f;

        float m = logit;
#pragma unroll
        for (int o = 32; o > 0; o >>= 1) m = fmaxf(m, __shfl_xor(m, o, 64));
        float ex = (l < Lsz) ? expf(logit - m) : 0.0f;
        float den = ex;
#pragma unroll
        for (int o = 32; o > 0; o >>= 1) den += __shfl_xor(den, o, 64);

        // argmax with first-index tie-break
        float av = logit; int ai = (l < Lsz) ? l : 63;
#pragma unroll
        for (int o = 32; o > 0; o >>= 1) {
            float ov = __shfl_xor(av, o, 64);
            int   oi = __shfl_xor(ai, o, 64);
            if (ov > av || (ov == av && oi < ai)) { av = ov; ai = oi; }
        }
        const float lse = m + logf(den);
        if (l < Lsz)
            out[(size_t)b * Lsz * Lsz + (size_t)t * Lsz + l] = logit - lse;
        if (l == 0) {
            out[(size_t)Bsz * Lsz * Lsz + (size_t)b * Lsz + t] = (float)ai;
            sel_s = ai;
        }
        int newm = ml | (l == ai);
        unsigned long long bal = __ballot(l >= Lsz ? 1 : newm);
        int all = (bal == 0xFFFFFFFFFFFFFFFFull);
        if (l < Lsz) mask[b * Lsz + l] = (all && l == Lsz - 1) ? 0 : newm;
    }
    __syncthreads();

    // ---- gather next decoder input ----
    {
        const int s = sel_s;
        dec[(size_t)b * 256 + tid] = emb[(size_t)s * Bsz * 256 + (size_t)b * 256 + tid];
    }
}

// ============================================================
extern "C" void kernel_launch(void* const* d_in, const int* in_sizes, int n_in,
                              void* d_out, int out_size, void* d_ws, size_t ws_size,
                              hipStream_t stream) {
    const float* decoder_input = (const float*)d_in[0];
    const float* emb           = (const float*)d_in[1];   // [L,B,E]
    const float* h0            = (const float*)d_in[2];
    const float* c0            = (const float*)d_in[3];
    const float* context       = (const float*)d_in[4];   // [L,B,H]
    const float* Wih    = (const float*)d_in[6];
    const float* Whh    = (const float*)d_in[7];
    const float* bih    = (const float*)d_in[8];
    const float* bhh    = (const float*)d_in[9];
    const float* glWq   = (const float*)d_in[10];
    const float* glbq   = (const float*)d_in[11];
    const float* glWref = (const float*)d_in[12];
    const float* glbref = (const float*)d_in[13];
    const float* glv    = (const float*)d_in[14];
    const float* ptWq   = (const float*)d_in[15];
    const float* ptbq   = (const float*)d_in[16];
    const float* ptWref = (const float*)d_in[17];
    const float* ptbref = (const float*)d_in[18];
    const float* ptv    = (const float*)d_in[19];

    float* out = (float*)d_out;

    // workspace layout (floats)
    float* ws    = (float*)d_ws;
    float* e_gl  = ws;                                    // [B,L,H]
    float* e_pt  = e_gl + (size_t)Bsz * Lsz * Hsz;        // [B,L,H]
    float* WqGlP = e_pt + (size_t)Bsz * Lsz * Hsz;        // [H,H] packed
    float* WqPtP = WqGlP + (size_t)Hsz * Hsz;
    float* hb0   = WqPtP + (size_t)Hsz * Hsz;
    float* hb1   = hb0 + (size_t)Bsz * Hsz;
    float* cb0   = hb1 + (size_t)Bsz * Hsz;
    float* cb1   = cb0 + (size_t)Bsz * Hsz;
    float* dec   = cb1 + (size_t)Bsz * Hsz;
    int*   mask  = (int*)(dec + (size_t)Bsz * Esz);       // [B,L]

    float* hbuf[2] = {hb0, hb1};
    float* cbuf[2] = {cb0, cb1};

    init_kernel<<<dim3(Bsz), dim3(256), 0, stream>>>(decoder_input, dec, mask);
    pack_wq<<<dim3(256, 2), dim3(256), 0, stream>>>(glWq, ptWq, WqGlP, WqPtP);

    eproj_kernel<<<dim3(6400), dim3(256), 0, stream>>>(
        context, glWref, glbref, e_gl, ptWref, ptbref, e_pt);

    for (int t = 0; t < Lsz; t++) {
        const float* hin = (t == 0) ? h0 : hbuf[(t + 1) & 1];
        const float* cin = (t == 0) ? c0 : cbuf[(t + 1) & 1];
        float* hout = hbuf[t & 1];
        float* cout = cbuf[t & 1];

        lstm_fused<<<dim3(32, 16), dim3(256), 0, stream>>>(
            dec, hin, cin, Wih, Whh, bih, bhh, hout, cout);

        attn_row<<<dim3(Bsz), dim3(256), 0, stream>>>(
            hout, WqGlP, glbq, e_gl, glv, WqPtP, ptbq, e_pt, ptv,
            mask, out, t, dec, emb);
    }
}